// Round 16
// baseline (548.430 us; speedup 1.0000x reference)
//
#include <hip/hip_runtime.h>
#include <hip/hip_bf16.h>
#include <cstdint>

// Problem constants
#define BB 64
#define SS 1024
#define DCn 64
#define Hn 128
#define G3 384
#define HPITCH 144   // shorts per h-row: pitch_dw=72 == 8 mod 32 -> <=2-way banks (free)

using f32x4 = __attribute__((ext_vector_type(4))) float;
using bf16x8 = __attribute__((ext_vector_type(8))) short;

// rcp-based sigmoid: avoids IEEE div sequence per call
__device__ __forceinline__ float sigmoid_f(float x) {
  return __builtin_amdgcn_rcpf(1.0f + __expf(-x));
}
__device__ __forceinline__ float tanh_f(float x) {
  float xc = fminf(fmaxf(x, -15.0f), 15.0f);
  float t = __expf(-2.0f * xc);
  return (1.0f - t) * __builtin_amdgcn_rcpf(1.0f + t);
}
__device__ __forceinline__ short f2bf(float x) {
  union { float f; uint32_t u; } v; v.f = x;
  uint32_t r = v.u + 0x7FFFu + ((v.u >> 16) & 1u);   // RNE
  return (short)(r >> 16);
}
__device__ __forceinline__ float bf2f(ushort u) {
  union { uint32_t i; float f; } v; v.i = (uint32_t)u << 16; return v.f;
}
__device__ __forceinline__ float sel4(f32x4 v, int q) {
  float t0 = (q & 1) ? v[1] : v[0];
  float t1 = (q & 1) ? v[3] : v[2];
  return (q & 2) ? t1 : t0;
}

#define LDS_BARRIER() do {                                   \
    asm volatile("s_waitcnt lgkmcnt(0)" ::: "memory");       \
    __builtin_amdgcn_s_barrier();                            \
    __builtin_amdgcn_sched_barrier(0);                       \
  } while (0)

// ---------------- weight conversion: W_ih -> bf16; Baug[144][128] =
// [mlp_w(128) ; pred_w[0:128] ; pred_w[128:256] ; zeros(14)]
__global__ __launch_bounds__(256) void convw_kernel(
    const float* __restrict__ W_ih, const float* __restrict__ mlp_w,
    const float* __restrict__ pred_w,
    ushort* __restrict__ Wihb, ushort* __restrict__ Baug) {
  int i = blockIdx.x * 256 + threadIdx.x;      // [0, 67584)
  if (i < 49152) { Wihb[i] = (ushort)f2bf(W_ih[i]); return; }
  int j = i - 49152;                           // [0, 18432)
  int r = j >> 7, k = j & 127;
  float v = (r < 128) ? mlp_w[j]
          : (r == 128) ? pred_w[k]
          : (r == 129) ? pred_w[128 + k] : 0.0f;
  Baug[j] = (ushort)f2bf(v);
}

// ---------------- FUSED embed + B1 GEMM: build inter-tile (64x128 bf16) in
// LDS (never hits HBM), stage ALL of Wihb (384x128 bf16, 96KB) in LDS, emit
// Xp[64 rows][384] bf16 + C3. 1024 blocks x 512 threads, 114KB LDS, 1 blk/CU.
__global__ __attribute__((amdgpu_flat_work_group_size(512, 512))) void embgemm_kernel(
    const int* __restrict__ qseq, const int* __restrict__ cseq,
    const int* __restrict__ q2c, const int* __restrict__ q2cm,
    const float* __restrict__ cemb, const float* __restrict__ remb,
    const float* __restrict__ pred_w, const ushort* __restrict__ Wihb,
    const float* __restrict__ b_ih,
    ushort* __restrict__ Xp, float* __restrict__ C3) {
  __shared__ bf16x8 Al[64][16];     // inter tile, swizzled chunks
  __shared__ bf16x8 Bl[384][16];    // all of W_ih, swizzled chunks
  const int m0 = blockIdx.x * 64;
  const int tid = threadIdx.x;
  // stage Wihb (6144 chunks / 512 thr = 12 each; L2-hot after first block)
  {
    const bf16x8* Bg = (const bf16x8*)Wihb;
    for (int i = tid; i < 384 * 16; i += 512) {
      int r = i >> 4, j = i & 15;
      Bl[r][j ^ (r & 15)] = Bg[i];
    }
  }
  // embed: 4 positions per iteration (2x 128-thread groups... tid>>7 in 0..3)
  ushort* Alus = (ushort*)Al;
  for (int it = 0; it < 16; ++it) {
    int prow = it * 4 + (tid >> 7);          // 0..63
    int pos = m0 + prow;
    int d = tid & 127;
    int q = qseq[pos];
    int corr = cseq[pos];
    float val;
    if (d < 64) {
      float acc = 0.f, msum = 0.f;
#pragma unroll
      for (int c = 0; c < 4; ++c) {
        int id = q2c[q * 4 + c];
        float m = (float)q2cm[q * 4 + c];
        acc += m * cemb[id * 64 + d];
        msum += m;
      }
      val = acc / fmaxf(msum, 1.0f);
      float p3 = val * pred_w[256 + d];      // d<64 lanes form a full wave
#pragma unroll
      for (int o = 32; o; o >>= 1) p3 += __shfl_down(p3, o);
      if (d == 0) C3[pos] = p3;
    } else {
      val = remb[corr * 64 + (d - 64)];
    }
    int slot = (corr == 1) ? d : ((d < 64) ? d + 64 : d - 64);
    Alus[prow * 128 + (((slot >> 3) ^ (prow & 15)) << 3) + (slot & 7)] =
        (ushort)f2bf(val);
  }
  __syncthreads();
  // GEMM: 24 col-tiles over 8 waves (3 each), 16 MFMA per col-tile
  const int w = tid >> 6, lane = tid & 63, ln = lane & 15, cc = lane >> 4;
  for (int nt = w; nt < 24; nt += 8) {
    bf16x8 bfr[4];
#pragma unroll
    for (int ks = 0; ks < 4; ++ks) bfr[ks] = Bl[nt * 16 + ln][(ks * 4 + cc) ^ ln];
    f32x4 C0 = {0,0,0,0}, C1 = {0,0,0,0}, C2 = {0,0,0,0}, C3v = {0,0,0,0};
#pragma unroll
    for (int ks = 0; ks < 4; ++ks) {
      bf16x8 a0 = Al[0 * 16 + ln][(ks * 4 + cc) ^ ln];
      bf16x8 a1 = Al[1 * 16 + ln][(ks * 4 + cc) ^ ln];
      bf16x8 a2 = Al[2 * 16 + ln][(ks * 4 + cc) ^ ln];
      bf16x8 a3 = Al[3 * 16 + ln][(ks * 4 + cc) ^ ln];
      C0 = __builtin_amdgcn_mfma_f32_16x16x32_bf16(a0, bfr[ks], C0, 0, 0, 0);
      C1 = __builtin_amdgcn_mfma_f32_16x16x32_bf16(a1, bfr[ks], C1, 0, 0, 0);
      C2 = __builtin_amdgcn_mfma_f32_16x16x32_bf16(a2, bfr[ks], C2, 0, 0, 0);
      C3v = __builtin_amdgcn_mfma_f32_16x16x32_bf16(a3, bfr[ks], C3v, 0, 0, 0);
    }
    const int col = nt * 16 + ln;
    const float bv = b_ih[col];
#pragma unroll
    for (int rt = 0; rt < 4; ++rt) {
      f32x4 Cf = (rt == 0) ? C0 : (rt == 1) ? C1 : (rt == 2) ? C2 : C3v;
#pragma unroll
      for (int q = 0; q < 4; ++q)
        Xp[(size_t)(m0 + rt * 16 + cc * 4 + q) * G3 + col] = (ushort)f2bf(Cf[q] + bv);
    }
  }
}

// ---------------- Phase C: MFMA GRU (structure verified R6-R15).
// R16: rnn_out stored bf16 (only ever consumed as bf16 by gemm_score).
__global__ __attribute__((amdgpu_flat_work_group_size(512, 512)))
__attribute__((amdgpu_waves_per_eu(2, 2))) void gru_kernel(
    const ushort* __restrict__ Xp, const float* __restrict__ W_hh,
    const float* __restrict__ b_hh, ushort* __restrict__ rnn_out) {
  const int tid = threadIdx.x;
  const int w = tid >> 6;
  const int lane = tid & 63;
  const int ln = lane & 15;
  const int c = lane >> 4;
  const int bl = ln & 3;
  const int qs = ln >> 2;
  const int b0 = blockIdx.x * 4;

  __shared__ alignas(16) short hlds[2][4 * HPITCH];

  bf16x8 wf[3][4];
#pragma unroll
  for (int gt = 0; gt < 3; ++gt) {
    const float* wr = W_hh + (size_t)(gt * 128 + w * 16 + ln) * 128 + c * 8;
#pragma unroll
    for (int ks = 0; ks < 4; ++ks) {
      bf16x8 f;
#pragma unroll
      for (int j = 0; j < 8; ++j) f[j] = f2bf(wr[ks * 32 + j]);
      wf[gt][ks] = f;
    }
  }
  const f32x4 br = *(const f32x4*)(b_hh + w * 16 + c * 4);
  const f32x4 bz = *(const f32x4*)(b_hh + 128 + w * 16 + c * 4);
  const f32x4 bn = *(const f32x4*)(b_hh + 256 + w * 16 + c * 4);

  for (int i = tid; i < 576; i += 512) ((uint32_t*)hlds)[i] = 0;

  const int dim = w * 16 + c * 4 + qs;
  const ushort* xs = Xp + (size_t)(b0 + bl) * SS * G3 + dim;
  ushort* rsp = rnn_out + (size_t)(b0 + bl) * SS * Hn + dim;

  ushort xr0 = xs[0], xz0 = xs[128], xn0 = xs[256];
  ushort xr1 = xs[G3 + 0], xz1 = xs[G3 + 128], xn1 = xs[G3 + 256];
  const ushort* xpf = xs + 2 * (size_t)G3;

  float h_old = 0.0f;
  LDS_BARRIER();

#define GRU_STEP(RB, XR, XZ, XN)                                             \
  {                                                                          \
    const short* hr = hlds[RB] + bl * HPITCH;                                \
    bf16x8 h0 = *(const bf16x8*)(hr + 0 * 32 + c * 8);                       \
    bf16x8 h1 = *(const bf16x8*)(hr + 1 * 32 + c * 8);                       \
    bf16x8 h2 = *(const bf16x8*)(hr + 2 * 32 + c * 8);                       \
    bf16x8 h3 = *(const bf16x8*)(hr + 3 * 32 + c * 8);                       \
    ushort pr = xpf[0], pz = xpf[128], pn = xpf[256];                        \
    xpf += G3;                                                               \
    __builtin_amdgcn_s_setprio(1);                                           \
    f32x4 ar = br, az = bz, an = bn;                                         \
    ar = __builtin_amdgcn_mfma_f32_16x16x32_bf16(wf[0][0], h0, ar, 0, 0, 0); \
    an = __builtin_amdgcn_mfma_f32_16x16x32_bf16(wf[2][0], h0, an, 0, 0, 0); \
    ar = __builtin_amdgcn_mfma_f32_16x16x32_bf16(wf[0][1], h1, ar, 0, 0, 0); \
    an = __builtin_amdgcn_mfma_f32_16x16x32_bf16(wf[2][1], h1, an, 0, 0, 0); \
    ar = __builtin_amdgcn_mfma_f32_16x16x32_bf16(wf[0][2], h2, ar, 0, 0, 0); \
    an = __builtin_amdgcn_mfma_f32_16x16x32_bf16(wf[2][2], h2, an, 0, 0, 0); \
    ar = __builtin_amdgcn_mfma_f32_16x16x32_bf16(wf[0][3], h3, ar, 0, 0, 0); \
    an = __builtin_amdgcn_mfma_f32_16x16x32_bf16(wf[2][3], h3, an, 0, 0, 0); \
    az = __builtin_amdgcn_mfma_f32_16x16x32_bf16(wf[1][0], h0, az, 0, 0, 0); \
    az = __builtin_amdgcn_mfma_f32_16x16x32_bf16(wf[1][1], h1, az, 0, 0, 0); \
    az = __builtin_amdgcn_mfma_f32_16x16x32_bf16(wf[1][2], h2, az, 0, 0, 0); \
    az = __builtin_amdgcn_mfma_f32_16x16x32_bf16(wf[1][3], h3, az, 0, 0, 0); \
    __builtin_amdgcn_s_setprio(0);                                           \
    float ga = sel4(ar, qs), gz = sel4(az, qs), gn = sel4(an, qs);           \
    float r = sigmoid_f(bf2f(XR) + ga);                                      \
    float a = bf2f(XN) + r * gn;                                             \
    float e = __expf(-2.0f * a);                                             \
    float n = 2.0f * __builtin_amdgcn_rcpf(1.0f + e) - 1.0f;                 \
    float z = sigmoid_f(bf2f(XZ) + gz);                                      \
    float hn = n + z * (h_old - n);                                          \
    h_old = hn;                                                              \
    ushort hb = (ushort)f2bf(hn);                                            \
    hlds[RB ^ 1][bl * HPITCH + dim] = (short)hb;                             \
    LDS_BARRIER();                                                           \
    *rsp = hb;                                                               \
    rsp += Hn;                                                               \
    XR = pr; XZ = pz; XN = pn;                                               \
  }

  for (int t = 0; t < SS; t += 2) {
    GRU_STEP(0, xr0, xz0, xn0)
    GRU_STEP(1, xr1, xz1, xn1)
  }
#undef GRU_STEP
}

// ---------------- Fused A2 GEMM + score + D-dots. Grid 1024 blocks, 256 thr.
// rnn now bf16 (straight chunk staging). Baug[144][128]: cols 0..127 ->
// tanh()*sim_w row-reduced into s; col 128 -> D1; col 129 -> D2.
__global__ __launch_bounds__(256) void gemm_score_kernel(
    const ushort* __restrict__ rnn, const ushort* __restrict__ Baug,
    const float* __restrict__ mlp_b, const float* __restrict__ sim_w,
    float* __restrict__ s, float* __restrict__ D1, float* __restrict__ D2) {
  __shared__ bf16x8 Al[64][16];
  __shared__ bf16x8 Bl[144][16];
  __shared__ float srow[64][4];
  const int m0 = blockIdx.x * 64;
  const int tid = threadIdx.x;
  {
    const int row = tid >> 2, j0 = (tid & 3) * 4;
    const bf16x8* A = (const bf16x8*)rnn + (size_t)(m0 + row) * 16 + j0;
#pragma unroll
    for (int jj = 0; jj < 4; ++jj) Al[row][(j0 + jj) ^ (row & 15)] = A[jj];
  }
  {
    const bf16x8* Bg = (const bf16x8*)Baug;
    for (int i = tid; i < 144 * 16; i += 256) {
      int r = i >> 4, j = i & 15;
      Bl[r][j ^ (r & 15)] = Bg[i];
    }
  }
  __syncthreads();
  const int w = tid >> 6, lane = tid & 63, ln = lane & 15, cc = lane >> 4;
  float racc[4][4] = {};
  for (int nt = w; nt < 9; nt += 4) {
    bf16x8 bfr[4];
#pragma unroll
    for (int ks = 0; ks < 4; ++ks) bfr[ks] = Bl[nt * 16 + ln][(ks * 4 + cc) ^ ln];
    f32x4 C0 = {0,0,0,0}, C1 = {0,0,0,0}, C2 = {0,0,0,0}, C3v = {0,0,0,0};
#pragma unroll
    for (int ks = 0; ks < 4; ++ks) {
      bf16x8 a0 = Al[0 * 16 + ln][(ks * 4 + cc) ^ ln];
      bf16x8 a1 = Al[1 * 16 + ln][(ks * 4 + cc) ^ ln];
      bf16x8 a2 = Al[2 * 16 + ln][(ks * 4 + cc) ^ ln];
      bf16x8 a3 = Al[3 * 16 + ln][(ks * 4 + cc) ^ ln];
      C0 = __builtin_amdgcn_mfma_f32_16x16x32_bf16(a0, bfr[ks], C0, 0, 0, 0);
      C1 = __builtin_amdgcn_mfma_f32_16x16x32_bf16(a1, bfr[ks], C1, 0, 0, 0);
      C2 = __builtin_amdgcn_mfma_f32_16x16x32_bf16(a2, bfr[ks], C2, 0, 0, 0);
      C3v = __builtin_amdgcn_mfma_f32_16x16x32_bf16(a3, bfr[ks], C3v, 0, 0, 0);
    }
    if (nt < 8) {
      const int col = nt * 16 + ln;
      const float bv = mlp_b[col];
      const float sw = sim_w[col];
#pragma unroll
      for (int rt = 0; rt < 4; ++rt) {
        f32x4 Cf = (rt == 0) ? C0 : (rt == 1) ? C1 : (rt == 2) ? C2 : C3v;
#pragma unroll
        for (int q = 0; q < 4; ++q)
          racc[rt][q] += tanh_f(Cf[q] + bv) * sw;
      }
    } else if (ln < 2) {
      float* Dp = (ln == 0) ? D1 : D2;
#pragma unroll
      for (int rt = 0; rt < 4; ++rt) {
        f32x4 Cf = (rt == 0) ? C0 : (rt == 1) ? C1 : (rt == 2) ? C2 : C3v;
#pragma unroll
        for (int q = 0; q < 4; ++q)
          Dp[m0 + rt * 16 + cc * 4 + q] = Cf[q];
      }
    }
  }
#pragma unroll
  for (int o = 1; o <= 8; o <<= 1)
#pragma unroll
    for (int rt = 0; rt < 4; ++rt)
#pragma unroll
      for (int q = 0; q < 4; ++q)
        racc[rt][q] += __shfl_xor(racc[rt][q], o);
  if (ln == 0)
#pragma unroll
    for (int rt = 0; rt < 4; ++rt)
#pragma unroll
      for (int q = 0; q < 4; ++q)
        srow[rt * 16 + cc * 4 + q][w] = racc[rt][q];
  __syncthreads();
  if (tid < 64)
    s[m0 + tid] = srow[tid][0] + srow[tid][1] + srow[tid][2] + srow[tid][3];
}

// ---------------- Fused attention + output (verified R15).
__global__ __launch_bounds__(128) void attn_final_kernel(
    const float* __restrict__ s, const float* __restrict__ D1,
    const float* __restrict__ D2, const float* __restrict__ C3,
    const float* __restrict__ pred_b, float* __restrict__ out) {
  const int b = blockIdx.x;
  const int tid = threadIdx.x;   // 128
  __shared__ float elds[SS];
  __shared__ float rcpd[SS];
  __shared__ float d1l[SS];
  __shared__ float dcl[SS];
  __shared__ float red[2];
  __shared__ float wtot[2];
  const float pb = pred_b[0];
  const float* sb = s + (size_t)b * SS;
  const float* d1b = D1 + (size_t)b * SS;
  const float* d2b = D2 + (size_t)b * SS;
  const float* c3b = C3 + (size_t)b * SS;
  float m = -1e30f;
  for (int i = tid; i < SS; i += 128) m = fmaxf(m, sb[i]);
#pragma unroll
  for (int o = 32; o; o >>= 1) m = fmaxf(m, __shfl_xor(m, o));
  if ((tid & 63) == 0) red[tid >> 6] = m;
  __syncthreads();
  m = fmaxf(red[0], red[1]);
  for (int i = tid; i < SS; i += 128) {
    elds[i] = __expf(sb[i] - m);
    d1l[i] = d1b[i];
    dcl[i] = d2b[i] + ((i < SS - 1) ? c3b[i + 1] : 0.0f) + pb;
  }
  __syncthreads();
  {
    const int base = tid * 8;
    float v[8];
    float run = 0.f;
#pragma unroll
    for (int k = 0; k < 8; ++k) { run += elds[base + k]; v[k] = run; }
    float tot = run, sc = tot;
#pragma unroll
    for (int o = 1; o < 64; o <<= 1) {
      float u = __shfl_up(sc, o);
      if ((tid & 63) >= o) sc += u;
    }
    if ((tid & 63) == 63) wtot[tid >> 6] = sc;
    __syncthreads();
    float excl = sc - tot;
    if (tid >= 64) excl += wtot[0];
#pragma unroll
    for (int k = 0; k < 8; ++k)
      rcpd[base + k] = __builtin_amdgcn_rcpf(v[k] + excl);
  }
  __syncthreads();
  float P_num = 0.f, P_run = 0.f;
  float* ob = out + (size_t)b * (SS - 1);
  for (int t = 0; t < SS; t += 4) {
    f32x4 e4 = *(const f32x4*)&elds[t];
    f32x4 r4 = *(const f32x4*)&rcpd[t];
    f32x4 d4 = *(const f32x4*)&d1l[t];
    f32x4 c4 = *(const f32x4*)&dcl[t];
#pragma unroll
    for (int k = 0; k < 4; ++k) {
      P_num += e4[k] * d4[k];
      float v = sigmoid_f(P_run + c4[k]);
      if (tid == 0 && (t + k) < SS - 1) ob[t + k] = v;
      P_run += P_num * r4[k];
    }
  }
}

extern "C" void kernel_launch(void* const* d_in, const int* in_sizes, int n_in,
                              void* d_out, int out_size, void* d_ws, size_t ws_size,
                              hipStream_t stream) {
  const int* qseq = (const int*)d_in[0];
  const int* cseq = (const int*)d_in[1];
  const int* q2c = (const int*)d_in[2];
  const int* q2cm = (const int*)d_in[3];
  const float* cemb = (const float*)d_in[4];
  const float* remb = (const float*)d_in[5];
  const float* mlp_w = (const float*)d_in[6];
  const float* mlp_b = (const float*)d_in[7];
  const float* sim_w = (const float*)d_in[8];
  const float* W_ih = (const float*)d_in[9];
  const float* b_ih = (const float*)d_in[10];
  const float* W_hh = (const float*)d_in[11];
  const float* b_hh = (const float*)d_in[12];
  const float* pred_w = (const float*)d_in[13];
  const float* pred_b = (const float*)d_in[14];
  float* out = (float*)d_out;

  // workspace layout -- ALL offsets in f32 slots (ushort counts halved).
  float* ws = (float*)d_ws;
  ushort* Xp = (ushort*)(ws + 4194304);      // 25,165,824 us = [4194304, 16777216)
  ushort* rnn = (ushort*)(ws + 16777216);    // 8,388,608 us = [16777216, 20971520)
  ushort* Wihb = (ushort*)(ws + 25165824);   // 49,152 us -> [25165824, 25190400)
  ushort* Baug = (ushort*)(ws + 25190400);   // 18,432 us -> [25190400, 25199616)
  float* sbuf = ws + 25199616;               // 65,536 f32
  float* D1 = ws + 25265152;                 // 65,536 f32
  float* D2 = ws + 25330688;                 // 65,536 f32
  float* C3 = ws + 25396224;                 // 65,536 f32

  convw_kernel<<<264, 256, 0, stream>>>(W_ih, mlp_w, pred_w, Wihb, Baug);
  embgemm_kernel<<<1024, 512, 0, stream>>>(qseq, cseq, q2c, q2cm, cemb, remb,
                                           pred_w, Wihb, b_ih, Xp, C3);
  gru_kernel<<<16, 512, 0, stream>>>(Xp, W_hh, b_hh, rnn);
  gemm_score_kernel<<<1024, 256, 0, stream>>>(rnn, Baug, mlp_b, sim_w,
                                              sbuf, D1, D2);
  attn_final_kernel<<<64, 128, 0, stream>>>(sbuf, D1, D2, C3, pred_b, out);
}

// Round 17
// 519.220 us; speedup vs baseline: 1.0563x; 1.0563x over previous
//
#include <hip/hip_runtime.h>
#include <hip/hip_bf16.h>
#include <cstdint>

// Problem constants
#define BB 64
#define SS 1024
#define DCn 64
#define Hn 128
#define G3 384
#define HPITCH 144   // shorts per h-row: pitch_dw=72 == 8 mod 32 -> <=2-way banks (free)

using f32x4 = __attribute__((ext_vector_type(4))) float;
using bf16x8 = __attribute__((ext_vector_type(8))) short;

// rcp-based sigmoid: avoids IEEE div sequence per call
__device__ __forceinline__ float sigmoid_f(float x) {
  return __builtin_amdgcn_rcpf(1.0f + __expf(-x));
}
__device__ __forceinline__ float tanh_f(float x) {
  float xc = fminf(fmaxf(x, -15.0f), 15.0f);
  float t = __expf(-2.0f * xc);
  return (1.0f - t) * __builtin_amdgcn_rcpf(1.0f + t);
}
__device__ __forceinline__ short f2bf(float x) {
  union { float f; uint32_t u; } v; v.f = x;
  uint32_t r = v.u + 0x7FFFu + ((v.u >> 16) & 1u);   // RNE
  return (short)(r >> 16);
}
__device__ __forceinline__ float bf2f(ushort u) {
  union { uint32_t i; float f; } v; v.i = (uint32_t)u << 16; return v.f;
}
__device__ __forceinline__ float sel4(f32x4 v, int q) {
  float t0 = (q & 1) ? v[1] : v[0];
  float t1 = (q & 1) ? v[3] : v[2];
  return (q & 2) ? t1 : t0;
}

#define LDS_BARRIER() do {                                   \
    asm volatile("s_waitcnt lgkmcnt(0)" ::: "memory");       \
    __builtin_amdgcn_s_barrier();                            \
    __builtin_amdgcn_sched_barrier(0);                       \
  } while (0)

// ---------------- weight conversion: W_ih -> bf16; Baug[144][128] =
// [mlp_w(128) ; pred_w[0:128] ; pred_w[128:256] ; zeros(14)]
__global__ __launch_bounds__(256) void convw_kernel(
    const float* __restrict__ W_ih, const float* __restrict__ mlp_w,
    const float* __restrict__ pred_w,
    ushort* __restrict__ Wihb, ushort* __restrict__ Baug) {
  int i = blockIdx.x * 256 + threadIdx.x;      // [0, 67584)
  if (i < 49152) { Wihb[i] = (ushort)f2bf(W_ih[i]); return; }
  int j = i - 49152;                           // [0, 18432)
  int r = j >> 7, k = j & 127;
  float v = (r < 128) ? mlp_w[j]
          : (r == 128) ? pred_w[k]
          : (r == 129) ? pred_w[128 + k] : 0.0f;
  Baug[j] = (ushort)f2bf(v);
}

// ---------------- Phase A: embeddings + concat -> interb(bf16); C3[pos] =
// concept(pos,:) . pred_w[256:320] reduced in-wave (concept never stored).
// Fat grid (32768 blocks) for gather-latency hiding -- R16's fused version
// collapsed this parallelism and regressed.
__global__ __launch_bounds__(256) void embed_kernel(
    const int* __restrict__ qseq, const int* __restrict__ cseq,
    const int* __restrict__ q2c, const int* __restrict__ q2cm,
    const float* __restrict__ cemb, const float* __restrict__ remb,
    const float* __restrict__ pred_w,
    ushort* __restrict__ interb, float* __restrict__ C3) {
  int pos = blockIdx.x * 2 + (threadIdx.x >> 7);   // [0, 65536)
  int d = threadIdx.x & 127;
  int q = qseq[pos];
  int corr = cseq[pos];
  float val;
  if (d < 64) {
    float acc = 0.f, msum = 0.f;
#pragma unroll
    for (int c = 0; c < 4; ++c) {
      int id = q2c[q * 4 + c];
      float m = (float)q2cm[q * 4 + c];
      acc += m * cemb[id * 64 + d];
      msum += m;
    }
    val = acc / fmaxf(msum, 1.0f);
    float p3 = val * pred_w[256 + d];
#pragma unroll
    for (int o = 32; o; o >>= 1) p3 += __shfl_down(p3, o);
    if (d == 0) C3[pos] = p3;
  } else {
    val = remb[corr * 64 + (d - 64)];
  }
  int slot = (corr == 1) ? d : ((d < 64) ? d + 64 : d - 64);
  interb[(size_t)pos * 128 + slot] = (ushort)f2bf(val);
}

// ---------------- B1 GEMM: Xp[64 rows][384] = interb-tile x Wihb^T + b_ih.
// 1024 blocks x 512 threads. A-tile (16KB) + ALL of Wihb (96KB) staged once
// per block (A fetched 1x vs R15's 6x). 112KB LDS -> 1 blk/CU, 4 rounds.
__global__ __attribute__((amdgpu_flat_work_group_size(512, 512))) void gemm_b1_kernel(
    const ushort* __restrict__ interb, const ushort* __restrict__ Wihb,
    const float* __restrict__ b_ih, ushort* __restrict__ Xp) {
  __shared__ bf16x8 Al[64][16];
  __shared__ bf16x8 Bl[384][16];
  const int m0 = blockIdx.x * 64;
  const int tid = threadIdx.x;
  {
    const bf16x8* Ag = (const bf16x8*)interb + (size_t)m0 * 16;
    for (int i = tid; i < 64 * 16; i += 512) {
      int r = i >> 4, j = i & 15;
      Al[r][j ^ (r & 15)] = Ag[i];
    }
    const bf16x8* Bg = (const bf16x8*)Wihb;
    for (int i = tid; i < 384 * 16; i += 512) {
      int r = i >> 4, j = i & 15;
      Bl[r][j ^ (r & 15)] = Bg[i];
    }
  }
  __syncthreads();
  const int w = tid >> 6, lane = tid & 63, ln = lane & 15, cc = lane >> 4;
  for (int nt = w; nt < 24; nt += 8) {
    bf16x8 bfr[4];
#pragma unroll
    for (int ks = 0; ks < 4; ++ks) bfr[ks] = Bl[nt * 16 + ln][(ks * 4 + cc) ^ ln];
    f32x4 C0 = {0,0,0,0}, C1 = {0,0,0,0}, C2 = {0,0,0,0}, C3v = {0,0,0,0};
#pragma unroll
    for (int ks = 0; ks < 4; ++ks) {
      bf16x8 a0 = Al[0 * 16 + ln][(ks * 4 + cc) ^ ln];
      bf16x8 a1 = Al[1 * 16 + ln][(ks * 4 + cc) ^ ln];
      bf16x8 a2 = Al[2 * 16 + ln][(ks * 4 + cc) ^ ln];
      bf16x8 a3 = Al[3 * 16 + ln][(ks * 4 + cc) ^ ln];
      C0 = __builtin_amdgcn_mfma_f32_16x16x32_bf16(a0, bfr[ks], C0, 0, 0, 0);
      C1 = __builtin_amdgcn_mfma_f32_16x16x32_bf16(a1, bfr[ks], C1, 0, 0, 0);
      C2 = __builtin_amdgcn_mfma_f32_16x16x32_bf16(a2, bfr[ks], C2, 0, 0, 0);
      C3v = __builtin_amdgcn_mfma_f32_16x16x32_bf16(a3, bfr[ks], C3v, 0, 0, 0);
    }
    const int col = nt * 16 + ln;
    const float bv = b_ih[col];
#pragma unroll
    for (int rt = 0; rt < 4; ++rt) {
      f32x4 Cf = (rt == 0) ? C0 : (rt == 1) ? C1 : (rt == 2) ? C2 : C3v;
#pragma unroll
      for (int q = 0; q < 4; ++q)
        Xp[(size_t)(m0 + rt * 16 + cc * 4 + q) * G3 + col] = (ushort)f2bf(Cf[q] + bv);
    }
  }
}

// ---------------- Phase C: MFMA GRU (structure verified R6-R16; bf16 rnn out)
__global__ __attribute__((amdgpu_flat_work_group_size(512, 512)))
__attribute__((amdgpu_waves_per_eu(2, 2))) void gru_kernel(
    const ushort* __restrict__ Xp, const float* __restrict__ W_hh,
    const float* __restrict__ b_hh, ushort* __restrict__ rnn_out) {
  const int tid = threadIdx.x;
  const int w = tid >> 6;
  const int lane = tid & 63;
  const int ln = lane & 15;
  const int c = lane >> 4;
  const int bl = ln & 3;
  const int qs = ln >> 2;
  const int b0 = blockIdx.x * 4;

  __shared__ alignas(16) short hlds[2][4 * HPITCH];

  bf16x8 wf[3][4];
#pragma unroll
  for (int gt = 0; gt < 3; ++gt) {
    const float* wr = W_hh + (size_t)(gt * 128 + w * 16 + ln) * 128 + c * 8;
#pragma unroll
    for (int ks = 0; ks < 4; ++ks) {
      bf16x8 f;
#pragma unroll
      for (int j = 0; j < 8; ++j) f[j] = f2bf(wr[ks * 32 + j]);
      wf[gt][ks] = f;
    }
  }
  const f32x4 br = *(const f32x4*)(b_hh + w * 16 + c * 4);
  const f32x4 bz = *(const f32x4*)(b_hh + 128 + w * 16 + c * 4);
  const f32x4 bn = *(const f32x4*)(b_hh + 256 + w * 16 + c * 4);

  for (int i = tid; i < 576; i += 512) ((uint32_t*)hlds)[i] = 0;

  const int dim = w * 16 + c * 4 + qs;
  const ushort* xs = Xp + (size_t)(b0 + bl) * SS * G3 + dim;
  ushort* rsp = rnn_out + (size_t)(b0 + bl) * SS * Hn + dim;

  ushort xr0 = xs[0], xz0 = xs[128], xn0 = xs[256];
  ushort xr1 = xs[G3 + 0], xz1 = xs[G3 + 128], xn1 = xs[G3 + 256];
  const ushort* xpf = xs + 2 * (size_t)G3;

  float h_old = 0.0f;
  LDS_BARRIER();

#define GRU_STEP(RB, XR, XZ, XN)                                             \
  {                                                                          \
    const short* hr = hlds[RB] + bl * HPITCH;                                \
    bf16x8 h0 = *(const bf16x8*)(hr + 0 * 32 + c * 8);                       \
    bf16x8 h1 = *(const bf16x8*)(hr + 1 * 32 + c * 8);                       \
    bf16x8 h2 = *(const bf16x8*)(hr + 2 * 32 + c * 8);                       \
    bf16x8 h3 = *(const bf16x8*)(hr + 3 * 32 + c * 8);                       \
    ushort pr = xpf[0], pz = xpf[128], pn = xpf[256];                        \
    xpf += G3;                                                               \
    __builtin_amdgcn_s_setprio(1);                                           \
    f32x4 ar = br, az = bz, an = bn;                                         \
    ar = __builtin_amdgcn_mfma_f32_16x16x32_bf16(wf[0][0], h0, ar, 0, 0, 0); \
    an = __builtin_amdgcn_mfma_f32_16x16x32_bf16(wf[2][0], h0, an, 0, 0, 0); \
    ar = __builtin_amdgcn_mfma_f32_16x16x32_bf16(wf[0][1], h1, ar, 0, 0, 0); \
    an = __builtin_amdgcn_mfma_f32_16x16x32_bf16(wf[2][1], h1, an, 0, 0, 0); \
    ar = __builtin_amdgcn_mfma_f32_16x16x32_bf16(wf[0][2], h2, ar, 0, 0, 0); \
    an = __builtin_amdgcn_mfma_f32_16x16x32_bf16(wf[2][2], h2, an, 0, 0, 0); \
    ar = __builtin_amdgcn_mfma_f32_16x16x32_bf16(wf[0][3], h3, ar, 0, 0, 0); \
    an = __builtin_amdgcn_mfma_f32_16x16x32_bf16(wf[2][3], h3, an, 0, 0, 0); \
    az = __builtin_amdgcn_mfma_f32_16x16x32_bf16(wf[1][0], h0, az, 0, 0, 0); \
    az = __builtin_amdgcn_mfma_f32_16x16x32_bf16(wf[1][1], h1, az, 0, 0, 0); \
    az = __builtin_amdgcn_mfma_f32_16x16x32_bf16(wf[1][2], h2, az, 0, 0, 0); \
    az = __builtin_amdgcn_mfma_f32_16x16x32_bf16(wf[1][3], h3, az, 0, 0, 0); \
    __builtin_amdgcn_s_setprio(0);                                           \
    float ga = sel4(ar, qs), gz = sel4(az, qs), gn = sel4(an, qs);           \
    float r = sigmoid_f(bf2f(XR) + ga);                                      \
    float a = bf2f(XN) + r * gn;                                             \
    float e = __expf(-2.0f * a);                                             \
    float n = 2.0f * __builtin_amdgcn_rcpf(1.0f + e) - 1.0f;                 \
    float z = sigmoid_f(bf2f(XZ) + gz);                                      \
    float hn = n + z * (h_old - n);                                          \
    h_old = hn;                                                              \
    ushort hb = (ushort)f2bf(hn);                                            \
    hlds[RB ^ 1][bl * HPITCH + dim] = (short)hb;                             \
    LDS_BARRIER();                                                           \
    *rsp = hb;                                                               \
    rsp += Hn;                                                               \
    XR = pr; XZ = pz; XN = pn;                                               \
  }

  for (int t = 0; t < SS; t += 2) {
    GRU_STEP(0, xr0, xz0, xn0)
    GRU_STEP(1, xr1, xz1, xn1)
  }
#undef GRU_STEP
}

// ---------------- Fused A2 GEMM + score + D-dots (bf16 rnn input).
__global__ __launch_bounds__(256) void gemm_score_kernel(
    const ushort* __restrict__ rnn, const ushort* __restrict__ Baug,
    const float* __restrict__ mlp_b, const float* __restrict__ sim_w,
    float* __restrict__ s, float* __restrict__ D1, float* __restrict__ D2) {
  __shared__ bf16x8 Al[64][16];
  __shared__ bf16x8 Bl[144][16];
  __shared__ float srow[64][4];
  const int m0 = blockIdx.x * 64;
  const int tid = threadIdx.x;
  {
    const int row = tid >> 2, j0 = (tid & 3) * 4;
    const bf16x8* A = (const bf16x8*)rnn + (size_t)(m0 + row) * 16 + j0;
#pragma unroll
    for (int jj = 0; jj < 4; ++jj) Al[row][(j0 + jj) ^ (row & 15)] = A[jj];
  }
  {
    const bf16x8* Bg = (const bf16x8*)Baug;
    for (int i = tid; i < 144 * 16; i += 256) {
      int r = i >> 4, j = i & 15;
      Bl[r][j ^ (r & 15)] = Bg[i];
    }
  }
  __syncthreads();
  const int w = tid >> 6, lane = tid & 63, ln = lane & 15, cc = lane >> 4;
  float racc[4][4] = {};
  for (int nt = w; nt < 9; nt += 4) {
    bf16x8 bfr[4];
#pragma unroll
    for (int ks = 0; ks < 4; ++ks) bfr[ks] = Bl[nt * 16 + ln][(ks * 4 + cc) ^ ln];
    f32x4 C0 = {0,0,0,0}, C1 = {0,0,0,0}, C2 = {0,0,0,0}, C3v = {0,0,0,0};
#pragma unroll
    for (int ks = 0; ks < 4; ++ks) {
      bf16x8 a0 = Al[0 * 16 + ln][(ks * 4 + cc) ^ ln];
      bf16x8 a1 = Al[1 * 16 + ln][(ks * 4 + cc) ^ ln];
      bf16x8 a2 = Al[2 * 16 + ln][(ks * 4 + cc) ^ ln];
      bf16x8 a3 = Al[3 * 16 + ln][(ks * 4 + cc) ^ ln];
      C0 = __builtin_amdgcn_mfma_f32_16x16x32_bf16(a0, bfr[ks], C0, 0, 0, 0);
      C1 = __builtin_amdgcn_mfma_f32_16x16x32_bf16(a1, bfr[ks], C1, 0, 0, 0);
      C2 = __builtin_amdgcn_mfma_f32_16x16x32_bf16(a2, bfr[ks], C2, 0, 0, 0);
      C3v = __builtin_amdgcn_mfma_f32_16x16x32_bf16(a3, bfr[ks], C3v, 0, 0, 0);
    }
    if (nt < 8) {
      const int col = nt * 16 + ln;
      const float bv = mlp_b[col];
      const float sw = sim_w[col];
#pragma unroll
      for (int rt = 0; rt < 4; ++rt) {
        f32x4 Cf = (rt == 0) ? C0 : (rt == 1) ? C1 : (rt == 2) ? C2 : C3v;
#pragma unroll
        for (int q = 0; q < 4; ++q)
          racc[rt][q] += tanh_f(Cf[q] + bv) * sw;
      }
    } else if (ln < 2) {
      float* Dp = (ln == 0) ? D1 : D2;
#pragma unroll
      for (int rt = 0; rt < 4; ++rt) {
        f32x4 Cf = (rt == 0) ? C0 : (rt == 1) ? C1 : (rt == 2) ? C2 : C3v;
#pragma unroll
        for (int q = 0; q < 4; ++q)
          Dp[m0 + rt * 16 + cc * 4 + q] = Cf[q];
      }
    }
  }
#pragma unroll
  for (int o = 1; o <= 8; o <<= 1)
#pragma unroll
    for (int rt = 0; rt < 4; ++rt)
#pragma unroll
      for (int q = 0; q < 4; ++q)
        racc[rt][q] += __shfl_xor(racc[rt][q], o);
  if (ln == 0)
#pragma unroll
    for (int rt = 0; rt < 4; ++rt)
#pragma unroll
      for (int q = 0; q < 4; ++q)
        srow[rt * 16 + cc * 4 + q][w] = racc[rt][q];
  __syncthreads();
  if (tid < 64)
    s[m0 + tid] = srow[tid][0] + srow[tid][1] + srow[tid][2] + srow[tid][3];
}

// ---------------- Fused attention + output (verified R15).
__global__ __launch_bounds__(128) void attn_final_kernel(
    const float* __restrict__ s, const float* __restrict__ D1,
    const float* __restrict__ D2, const float* __restrict__ C3,
    const float* __restrict__ pred_b, float* __restrict__ out) {
  const int b = blockIdx.x;
  const int tid = threadIdx.x;   // 128
  __shared__ float elds[SS];
  __shared__ float rcpd[SS];
  __shared__ float d1l[SS];
  __shared__ float dcl[SS];
  __shared__ float red[2];
  __shared__ float wtot[2];
  const float pb = pred_b[0];
  const float* sb = s + (size_t)b * SS;
  const float* d1b = D1 + (size_t)b * SS;
  const float* d2b = D2 + (size_t)b * SS;
  const float* c3b = C3 + (size_t)b * SS;
  float m = -1e30f;
  for (int i = tid; i < SS; i += 128) m = fmaxf(m, sb[i]);
#pragma unroll
  for (int o = 32; o; o >>= 1) m = fmaxf(m, __shfl_xor(m, o));
  if ((tid & 63) == 0) red[tid >> 6] = m;
  __syncthreads();
  m = fmaxf(red[0], red[1]);
  for (int i = tid; i < SS; i += 128) {
    elds[i] = __expf(sb[i] - m);
    d1l[i] = d1b[i];
    dcl[i] = d2b[i] + ((i < SS - 1) ? c3b[i + 1] : 0.0f) + pb;
  }
  __syncthreads();
  {
    const int base = tid * 8;
    float v[8];
    float run = 0.f;
#pragma unroll
    for (int k = 0; k < 8; ++k) { run += elds[base + k]; v[k] = run; }
    float tot = run, sc = tot;
#pragma unroll
    for (int o = 1; o < 64; o <<= 1) {
      float u = __shfl_up(sc, o);
      if ((tid & 63) >= o) sc += u;
    }
    if ((tid & 63) == 63) wtot[tid >> 6] = sc;
    __syncthreads();
    float excl = sc - tot;
    if (tid >= 64) excl += wtot[0];
#pragma unroll
    for (int k = 0; k < 8; ++k)
      rcpd[base + k] = __builtin_amdgcn_rcpf(v[k] + excl);
  }
  __syncthreads();
  float P_num = 0.f, P_run = 0.f;
  float* ob = out + (size_t)b * (SS - 1);
  for (int t = 0; t < SS; t += 4) {
    f32x4 e4 = *(const f32x4*)&elds[t];
    f32x4 r4 = *(const f32x4*)&rcpd[t];
    f32x4 d4 = *(const f32x4*)&d1l[t];
    f32x4 c4 = *(const f32x4*)&dcl[t];
#pragma unroll
    for (int k = 0; k < 4; ++k) {
      P_num += e4[k] * d4[k];
      float v = sigmoid_f(P_run + c4[k]);
      if (tid == 0 && (t + k) < SS - 1) ob[t + k] = v;
      P_run += P_num * r4[k];
    }
  }
}

extern "C" void kernel_launch(void* const* d_in, const int* in_sizes, int n_in,
                              void* d_out, int out_size, void* d_ws, size_t ws_size,
                              hipStream_t stream) {
  const int* qseq = (const int*)d_in[0];
  const int* cseq = (const int*)d_in[1];
  const int* q2c = (const int*)d_in[2];
  const int* q2cm = (const int*)d_in[3];
  const float* cemb = (const float*)d_in[4];
  const float* remb = (const float*)d_in[5];
  const float* mlp_w = (const float*)d_in[6];
  const float* mlp_b = (const float*)d_in[7];
  const float* sim_w = (const float*)d_in[8];
  const float* W_ih = (const float*)d_in[9];
  const float* b_ih = (const float*)d_in[10];
  const float* W_hh = (const float*)d_in[11];
  const float* b_hh = (const float*)d_in[12];
  const float* pred_w = (const float*)d_in[13];
  const float* pred_b = (const float*)d_in[14];
  float* out = (float*)d_out;

  // workspace layout -- ALL offsets in f32 slots (ushort counts halved).
  float* ws = (float*)d_ws;
  ushort* interb = (ushort*)ws;              // 8,388,608 us = [0, 4194304)
  ushort* Xp = (ushort*)(ws + 4194304);      // 25,165,824 us = [4194304, 16777216)
  ushort* rnn = (ushort*)(ws + 16777216);    // 8,388,608 us = [16777216, 20971520)
  ushort* Wihb = (ushort*)(ws + 25165824);   // 49,152 us -> [25165824, 25190400)
  ushort* Baug = (ushort*)(ws + 25190400);   // 18,432 us -> [25190400, 25199616)
  float* sbuf = ws + 25199616;               // 65,536 f32
  float* D1 = ws + 25265152;                 // 65,536 f32
  float* D2 = ws + 25330688;                 // 65,536 f32
  float* C3 = ws + 25396224;                 // 65,536 f32

  convw_kernel<<<264, 256, 0, stream>>>(W_ih, mlp_w, pred_w, Wihb, Baug);
  embed_kernel<<<32768, 256, 0, stream>>>(qseq, cseq, q2c, q2cm, cemb, remb,
                                          pred_w, interb, C3);
  gemm_b1_kernel<<<1024, 512, 0, stream>>>(interb, Wihb, b_ih, Xp);
  gru_kernel<<<16, 512, 0, stream>>>(Xp, W_hh, b_hh, rnn);
  gemm_score_kernel<<<1024, 256, 0, stream>>>(rnn, Baug, mlp_b, sim_w,
                                              sbuf, D1, D2);
  attn_final_kernel<<<64, 128, 0, stream>>>(sbuf, D1, D2, C3, pred_b, out);
}

// Round 18
// 513.004 us; speedup vs baseline: 1.0691x; 1.0121x over previous
//
#include <hip/hip_runtime.h>
#include <hip/hip_bf16.h>
#include <cstdint>

// Problem constants
#define BB 64
#define SS 1024
#define DCn 64
#define Hn 128
#define G3 384
#define HPITCH 144   // shorts per h-row: pitch_dw=72 == 8 mod 32 -> <=2-way banks (free)

using f32x4 = __attribute__((ext_vector_type(4))) float;
using bf16x8 = __attribute__((ext_vector_type(8))) short;

// rcp-based sigmoid: avoids IEEE div sequence per call
__device__ __forceinline__ float sigmoid_f(float x) {
  return __builtin_amdgcn_rcpf(1.0f + __expf(-x));
}
__device__ __forceinline__ float tanh_f(float x) {
  float xc = fminf(fmaxf(x, -15.0f), 15.0f);
  float t = __expf(-2.0f * xc);
  return (1.0f - t) * __builtin_amdgcn_rcpf(1.0f + t);
}
__device__ __forceinline__ short f2bf(float x) {
  union { float f; uint32_t u; } v; v.f = x;
  uint32_t r = v.u + 0x7FFFu + ((v.u >> 16) & 1u);   // RNE
  return (short)(r >> 16);
}
__device__ __forceinline__ float bf2f(ushort u) {
  union { uint32_t i; float f; } v; v.i = (uint32_t)u << 16; return v.f;
}
__device__ __forceinline__ float sel4(f32x4 v, int q) {
  float t0 = (q & 1) ? v[1] : v[0];
  float t1 = (q & 1) ? v[3] : v[2];
  return (q & 2) ? t1 : t0;
}

#define LDS_BARRIER() do {                                   \
    asm volatile("s_waitcnt lgkmcnt(0)" ::: "memory");       \
    __builtin_amdgcn_s_barrier();                            \
    __builtin_amdgcn_sched_barrier(0);                       \
  } while (0)

// ---------------- weight conversion: W_ih -> bf16; Baug[144][128] =
// [mlp_w(128) ; pred_w[0:128] ; pred_w[128:256] ; zeros(14)]
__global__ __launch_bounds__(256) void convw_kernel(
    const float* __restrict__ W_ih, const float* __restrict__ mlp_w,
    const float* __restrict__ pred_w,
    ushort* __restrict__ Wihb, ushort* __restrict__ Baug) {
  int i = blockIdx.x * 256 + threadIdx.x;      // [0, 67584)
  if (i < 49152) { Wihb[i] = (ushort)f2bf(W_ih[i]); return; }
  int j = i - 49152;                           // [0, 18432)
  int r = j >> 7, k = j & 127;
  float v = (r < 128) ? mlp_w[j]
          : (r == 128) ? pred_w[k]
          : (r == 129) ? pred_w[128 + k] : 0.0f;
  Baug[j] = (ushort)f2bf(v);
}

// ---------------- Phase A: embeddings + concat -> interb(bf16); C3[pos] =
// concept(pos,:) . pred_w[256:320] reduced in-wave (concept never stored).
__global__ __launch_bounds__(256) void embed_kernel(
    const int* __restrict__ qseq, const int* __restrict__ cseq,
    const int* __restrict__ q2c, const int* __restrict__ q2cm,
    const float* __restrict__ cemb, const float* __restrict__ remb,
    const float* __restrict__ pred_w,
    ushort* __restrict__ interb, float* __restrict__ C3) {
  int pos = blockIdx.x * 2 + (threadIdx.x >> 7);   // [0, 65536)
  int d = threadIdx.x & 127;
  int q = qseq[pos];
  int corr = cseq[pos];
  float val;
  if (d < 64) {
    float acc = 0.f, msum = 0.f;
#pragma unroll
    for (int c = 0; c < 4; ++c) {
      int id = q2c[q * 4 + c];
      float m = (float)q2cm[q * 4 + c];
      acc += m * cemb[id * 64 + d];
      msum += m;
    }
    val = acc / fmaxf(msum, 1.0f);
    float p3 = val * pred_w[256 + d];
#pragma unroll
    for (int o = 32; o; o >>= 1) p3 += __shfl_down(p3, o);
    if (d == 0) C3[pos] = p3;
  } else {
    val = remb[corr * 64 + (d - 64)];
  }
  int slot = (corr == 1) ? d : ((d < 64) ? d + 64 : d - 64);
  interb[(size_t)pos * 128 + slot] = (ushort)f2bf(val);
}

// ---------------- B1 MFMA GEMM (R15-verified form): 64x64 tile, K=128
// one-shot, 256 threads, dim3(1024,6) grid. bf16 in, bf16 out.
__global__ __launch_bounds__(256) void gemm_mfma_kernel(
    const ushort* __restrict__ Ap, const ushort* __restrict__ Bp,
    const float* __restrict__ bias, ushort* __restrict__ Cp, int N) {
  __shared__ bf16x8 Al[64][16];
  __shared__ bf16x8 Bl[64][16];
  const int m0 = blockIdx.x * 64, n0 = blockIdx.y * 64;
  const int tid = threadIdx.x;
  const int row = tid >> 2, j0 = (tid & 3) * 4;
  {
    const bf16x8* A = (const bf16x8*)Ap + (size_t)(m0 + row) * 16 + j0;
#pragma unroll
    for (int jj = 0; jj < 4; ++jj) Al[row][(j0 + jj) ^ (row & 15)] = A[jj];
    const bf16x8* Bg = (const bf16x8*)Bp + (size_t)(n0 + row) * 16 + j0;
#pragma unroll
    for (int jj = 0; jj < 4; ++jj) Bl[row][(j0 + jj) ^ (row & 15)] = Bg[jj];
  }
  __syncthreads();
  const int w = tid >> 6, lane = tid & 63, ln = lane & 15, cc = lane >> 4;
  bf16x8 bfr[4];
#pragma unroll
  for (int ks = 0; ks < 4; ++ks) bfr[ks] = Bl[w * 16 + ln][(ks * 4 + cc) ^ ln];
  f32x4 C0 = {0,0,0,0}, C1 = {0,0,0,0}, C2 = {0,0,0,0}, C3v = {0,0,0,0};
#pragma unroll
  for (int ks = 0; ks < 4; ++ks) {
    bf16x8 a0 = Al[0 * 16 + ln][(ks * 4 + cc) ^ ln];
    bf16x8 a1 = Al[1 * 16 + ln][(ks * 4 + cc) ^ ln];
    bf16x8 a2 = Al[2 * 16 + ln][(ks * 4 + cc) ^ ln];
    bf16x8 a3 = Al[3 * 16 + ln][(ks * 4 + cc) ^ ln];
    C0 = __builtin_amdgcn_mfma_f32_16x16x32_bf16(a0, bfr[ks], C0, 0, 0, 0);
    C1 = __builtin_amdgcn_mfma_f32_16x16x32_bf16(a1, bfr[ks], C1, 0, 0, 0);
    C2 = __builtin_amdgcn_mfma_f32_16x16x32_bf16(a2, bfr[ks], C2, 0, 0, 0);
    C3v = __builtin_amdgcn_mfma_f32_16x16x32_bf16(a3, bfr[ks], C3v, 0, 0, 0);
  }
  const float bv = bias[n0 + w * 16 + ln];
  const size_t ncol = n0 + w * 16 + ln;
#pragma unroll
  for (int rt = 0; rt < 4; ++rt) {
    f32x4 Cf = (rt == 0) ? C0 : (rt == 1) ? C1 : (rt == 2) ? C2 : C3v;
#pragma unroll
    for (int q = 0; q < 4; ++q)
      Cp[(size_t)(m0 + rt * 16 + cc * 4 + q) * N + ncol] = (ushort)f2bf(Cf[q] + bv);
  }
}

// ---------------- Phase C: MFMA GRU (structure verified R6-R17; bf16 rnn out)
__global__ __attribute__((amdgpu_flat_work_group_size(512, 512)))
__attribute__((amdgpu_waves_per_eu(2, 2))) void gru_kernel(
    const ushort* __restrict__ Xp, const float* __restrict__ W_hh,
    const float* __restrict__ b_hh, ushort* __restrict__ rnn_out) {
  const int tid = threadIdx.x;
  const int w = tid >> 6;
  const int lane = tid & 63;
  const int ln = lane & 15;
  const int c = lane >> 4;
  const int bl = ln & 3;
  const int qs = ln >> 2;
  const int b0 = blockIdx.x * 4;

  __shared__ alignas(16) short hlds[2][4 * HPITCH];

  bf16x8 wf[3][4];
#pragma unroll
  for (int gt = 0; gt < 3; ++gt) {
    const float* wr = W_hh + (size_t)(gt * 128 + w * 16 + ln) * 128 + c * 8;
#pragma unroll
    for (int ks = 0; ks < 4; ++ks) {
      bf16x8 f;
#pragma unroll
      for (int j = 0; j < 8; ++j) f[j] = f2bf(wr[ks * 32 + j]);
      wf[gt][ks] = f;
    }
  }
  const f32x4 br = *(const f32x4*)(b_hh + w * 16 + c * 4);
  const f32x4 bz = *(const f32x4*)(b_hh + 128 + w * 16 + c * 4);
  const f32x4 bn = *(const f32x4*)(b_hh + 256 + w * 16 + c * 4);

  for (int i = tid; i < 576; i += 512) ((uint32_t*)hlds)[i] = 0;

  const int dim = w * 16 + c * 4 + qs;
  const ushort* xs = Xp + (size_t)(b0 + bl) * SS * G3 + dim;
  ushort* rsp = rnn_out + (size_t)(b0 + bl) * SS * Hn + dim;

  ushort xr0 = xs[0], xz0 = xs[128], xn0 = xs[256];
  ushort xr1 = xs[G3 + 0], xz1 = xs[G3 + 128], xn1 = xs[G3 + 256];
  const ushort* xpf = xs + 2 * (size_t)G3;

  float h_old = 0.0f;
  LDS_BARRIER();

#define GRU_STEP(RB, XR, XZ, XN)                                             \
  {                                                                          \
    const short* hr = hlds[RB] + bl * HPITCH;                                \
    bf16x8 h0 = *(const bf16x8*)(hr + 0 * 32 + c * 8);                       \
    bf16x8 h1 = *(const bf16x8*)(hr + 1 * 32 + c * 8);                       \
    bf16x8 h2 = *(const bf16x8*)(hr + 2 * 32 + c * 8);                       \
    bf16x8 h3 = *(const bf16x8*)(hr + 3 * 32 + c * 8);                       \
    ushort pr = xpf[0], pz = xpf[128], pn = xpf[256];                        \
    xpf += G3;                                                               \
    __builtin_amdgcn_s_setprio(1);                                           \
    f32x4 ar = br, az = bz, an = bn;                                         \
    ar = __builtin_amdgcn_mfma_f32_16x16x32_bf16(wf[0][0], h0, ar, 0, 0, 0); \
    an = __builtin_amdgcn_mfma_f32_16x16x32_bf16(wf[2][0], h0, an, 0, 0, 0); \
    ar = __builtin_amdgcn_mfma_f32_16x16x32_bf16(wf[0][1], h1, ar, 0, 0, 0); \
    an = __builtin_amdgcn_mfma_f32_16x16x32_bf16(wf[2][1], h1, an, 0, 0, 0); \
    ar = __builtin_amdgcn_mfma_f32_16x16x32_bf16(wf[0][2], h2, ar, 0, 0, 0); \
    an = __builtin_amdgcn_mfma_f32_16x16x32_bf16(wf[2][2], h2, an, 0, 0, 0); \
    ar = __builtin_amdgcn_mfma_f32_16x16x32_bf16(wf[0][3], h3, ar, 0, 0, 0); \
    an = __builtin_amdgcn_mfma_f32_16x16x32_bf16(wf[2][3], h3, an, 0, 0, 0); \
    az = __builtin_amdgcn_mfma_f32_16x16x32_bf16(wf[1][0], h0, az, 0, 0, 0); \
    az = __builtin_amdgcn_mfma_f32_16x16x32_bf16(wf[1][1], h1, az, 0, 0, 0); \
    az = __builtin_amdgcn_mfma_f32_16x16x32_bf16(wf[1][2], h2, az, 0, 0, 0); \
    az = __builtin_amdgcn_mfma_f32_16x16x32_bf16(wf[1][3], h3, az, 0, 0, 0); \
    __builtin_amdgcn_s_setprio(0);                                           \
    float ga = sel4(ar, qs), gz = sel4(az, qs), gn = sel4(an, qs);           \
    float r = sigmoid_f(bf2f(XR) + ga);                                      \
    float a = bf2f(XN) + r * gn;                                             \
    float e = __expf(-2.0f * a);                                             \
    float n = 2.0f * __builtin_amdgcn_rcpf(1.0f + e) - 1.0f;                 \
    float z = sigmoid_f(bf2f(XZ) + gz);                                      \
    float hn = n + z * (h_old - n);                                          \
    h_old = hn;                                                              \
    ushort hb = (ushort)f2bf(hn);                                            \
    hlds[RB ^ 1][bl * HPITCH + dim] = (short)hb;                             \
    LDS_BARRIER();                                                           \
    *rsp = hb;                                                               \
    rsp += Hn;                                                               \
    XR = pr; XZ = pz; XN = pn;                                               \
  }

  for (int t = 0; t < SS; t += 2) {
    GRU_STEP(0, xr0, xz0, xn0)
    GRU_STEP(1, xr1, xz1, xn1)
  }
#undef GRU_STEP
}

// ---------------- Fused A2 GEMM + score + D-dots (bf16 rnn input).
__global__ __launch_bounds__(256) void gemm_score_kernel(
    const ushort* __restrict__ rnn, const ushort* __restrict__ Baug,
    const float* __restrict__ mlp_b, const float* __restrict__ sim_w,
    float* __restrict__ s, float* __restrict__ D1, float* __restrict__ D2) {
  __shared__ bf16x8 Al[64][16];
  __shared__ bf16x8 Bl[144][16];
  __shared__ float srow[64][4];
  const int m0 = blockIdx.x * 64;
  const int tid = threadIdx.x;
  {
    const int row = tid >> 2, j0 = (tid & 3) * 4;
    const bf16x8* A = (const bf16x8*)rnn + (size_t)(m0 + row) * 16 + j0;
#pragma unroll
    for (int jj = 0; jj < 4; ++jj) Al[row][(j0 + jj) ^ (row & 15)] = A[jj];
  }
  {
    const bf16x8* Bg = (const bf16x8*)Baug;
    for (int i = tid; i < 144 * 16; i += 256) {
      int r = i >> 4, j = i & 15;
      Bl[r][j ^ (r & 15)] = Bg[i];
    }
  }
  __syncthreads();
  const int w = tid >> 6, lane = tid & 63, ln = lane & 15, cc = lane >> 4;
  float racc[4][4] = {};
  for (int nt = w; nt < 9; nt += 4) {
    bf16x8 bfr[4];
#pragma unroll
    for (int ks = 0; ks < 4; ++ks) bfr[ks] = Bl[nt * 16 + ln][(ks * 4 + cc) ^ ln];
    f32x4 C0 = {0,0,0,0}, C1 = {0,0,0,0}, C2 = {0,0,0,0}, C3v = {0,0,0,0};
#pragma unroll
    for (int ks = 0; ks < 4; ++ks) {
      bf16x8 a0 = Al[0 * 16 + ln][(ks * 4 + cc) ^ ln];
      bf16x8 a1 = Al[1 * 16 + ln][(ks * 4 + cc) ^ ln];
      bf16x8 a2 = Al[2 * 16 + ln][(ks * 4 + cc) ^ ln];
      bf16x8 a3 = Al[3 * 16 + ln][(ks * 4 + cc) ^ ln];
      C0 = __builtin_amdgcn_mfma_f32_16x16x32_bf16(a0, bfr[ks], C0, 0, 0, 0);
      C1 = __builtin_amdgcn_mfma_f32_16x16x32_bf16(a1, bfr[ks], C1, 0, 0, 0);
      C2 = __builtin_amdgcn_mfma_f32_16x16x32_bf16(a2, bfr[ks], C2, 0, 0, 0);
      C3v = __builtin_amdgcn_mfma_f32_16x16x32_bf16(a3, bfr[ks], C3v, 0, 0, 0);
    }
    if (nt < 8) {
      const int col = nt * 16 + ln;
      const float bv = mlp_b[col];
      const float sw = sim_w[col];
#pragma unroll
      for (int rt = 0; rt < 4; ++rt) {
        f32x4 Cf = (rt == 0) ? C0 : (rt == 1) ? C1 : (rt == 2) ? C2 : C3v;
#pragma unroll
        for (int q = 0; q < 4; ++q)
          racc[rt][q] += tanh_f(Cf[q] + bv) * sw;
      }
    } else if (ln < 2) {
      float* Dp = (ln == 0) ? D1 : D2;
#pragma unroll
      for (int rt = 0; rt < 4; ++rt) {
        f32x4 Cf = (rt == 0) ? C0 : (rt == 1) ? C1 : (rt == 2) ? C2 : C3v;
#pragma unroll
        for (int q = 0; q < 4; ++q)
          Dp[m0 + rt * 16 + cc * 4 + q] = Cf[q];
      }
    }
  }
#pragma unroll
  for (int o = 1; o <= 8; o <<= 1)
#pragma unroll
    for (int rt = 0; rt < 4; ++rt)
#pragma unroll
      for (int q = 0; q < 4; ++q)
        racc[rt][q] += __shfl_xor(racc[rt][q], o);
  if (ln == 0)
#pragma unroll
    for (int rt = 0; rt < 4; ++rt)
#pragma unroll
      for (int q = 0; q < 4; ++q)
        srow[rt * 16 + cc * 4 + q][w] = racc[rt][q];
  __syncthreads();
  if (tid < 64)
    s[m0 + tid] = srow[tid][0] + srow[tid][1] + srow[tid][2] + srow[tid][3];
}

// ---------------- Fused attention + output (verified R15).
__global__ __launch_bounds__(128) void attn_final_kernel(
    const float* __restrict__ s, const float* __restrict__ D1,
    const float* __restrict__ D2, const float* __restrict__ C3,
    const float* __restrict__ pred_b, float* __restrict__ out) {
  const int b = blockIdx.x;
  const int tid = threadIdx.x;   // 128
  __shared__ float elds[SS];
  __shared__ float rcpd[SS];
  __shared__ float d1l[SS];
  __shared__ float dcl[SS];
  __shared__ float red[2];
  __shared__ float wtot[2];
  const float pb = pred_b[0];
  const float* sb = s + (size_t)b * SS;
  const float* d1b = D1 + (size_t)b * SS;
  const float* d2b = D2 + (size_t)b * SS;
  const float* c3b = C3 + (size_t)b * SS;
  float m = -1e30f;
  for (int i = tid; i < SS; i += 128) m = fmaxf(m, sb[i]);
#pragma unroll
  for (int o = 32; o; o >>= 1) m = fmaxf(m, __shfl_xor(m, o));
  if ((tid & 63) == 0) red[tid >> 6] = m;
  __syncthreads();
  m = fmaxf(red[0], red[1]);
  for (int i = tid; i < SS; i += 128) {
    elds[i] = __expf(sb[i] - m);
    d1l[i] = d1b[i];
    dcl[i] = d2b[i] + ((i < SS - 1) ? c3b[i + 1] : 0.0f) + pb;
  }
  __syncthreads();
  {
    const int base = tid * 8;
    float v[8];
    float run = 0.f;
#pragma unroll
    for (int k = 0; k < 8; ++k) { run += elds[base + k]; v[k] = run; }
    float tot = run, sc = tot;
#pragma unroll
    for (int o = 1; o < 64; o <<= 1) {
      float u = __shfl_up(sc, o);
      if ((tid & 63) >= o) sc += u;
    }
    if ((tid & 63) == 63) wtot[tid >> 6] = sc;
    __syncthreads();
    float excl = sc - tot;
    if (tid >= 64) excl += wtot[0];
#pragma unroll
    for (int k = 0; k < 8; ++k)
      rcpd[base + k] = __builtin_amdgcn_rcpf(v[k] + excl);
  }
  __syncthreads();
  float P_num = 0.f, P_run = 0.f;
  float* ob = out + (size_t)b * (SS - 1);
  for (int t = 0; t < SS; t += 4) {
    f32x4 e4 = *(const f32x4*)&elds[t];
    f32x4 r4 = *(const f32x4*)&rcpd[t];
    f32x4 d4 = *(const f32x4*)&d1l[t];
    f32x4 c4 = *(const f32x4*)&dcl[t];
#pragma unroll
    for (int k = 0; k < 4; ++k) {
      P_num += e4[k] * d4[k];
      float v = sigmoid_f(P_run + c4[k]);
      if (tid == 0 && (t + k) < SS - 1) ob[t + k] = v;
      P_run += P_num * r4[k];
    }
  }
}

extern "C" void kernel_launch(void* const* d_in, const int* in_sizes, int n_in,
                              void* d_out, int out_size, void* d_ws, size_t ws_size,
                              hipStream_t stream) {
  const int* qseq = (const int*)d_in[0];
  const int* cseq = (const int*)d_in[1];
  const int* q2c = (const int*)d_in[2];
  const int* q2cm = (const int*)d_in[3];
  const float* cemb = (const float*)d_in[4];
  const float* remb = (const float*)d_in[5];
  const float* mlp_w = (const float*)d_in[6];
  const float* mlp_b = (const float*)d_in[7];
  const float* sim_w = (const float*)d_in[8];
  const float* W_ih = (const float*)d_in[9];
  const float* b_ih = (const float*)d_in[10];
  const float* W_hh = (const float*)d_in[11];
  const float* b_hh = (const float*)d_in[12];
  const float* pred_w = (const float*)d_in[13];
  const float* pred_b = (const float*)d_in[14];
  float* out = (float*)d_out;

  // workspace layout -- ALL offsets in f32 slots (ushort counts halved).
  float* ws = (float*)d_ws;
  ushort* interb = (ushort*)ws;              // 8,388,608 us = [0, 4194304)
  ushort* Xp = (ushort*)(ws + 4194304);      // 25,165,824 us = [4194304, 16777216)
  ushort* rnn = (ushort*)(ws + 16777216);    // 8,388,608 us = [16777216, 20971520)
  ushort* Wihb = (ushort*)(ws + 25165824);   // 49,152 us -> [25165824, 25190400)
  ushort* Baug = (ushort*)(ws + 25190400);   // 18,432 us -> [25190400, 25199616)
  float* sbuf = ws + 25199616;               // 65,536 f32
  float* D1 = ws + 25265152;                 // 65,536 f32
  float* D2 = ws + 25330688;                 // 65,536 f32
  float* C3 = ws + 25396224;                 // 65,536 f32

  convw_kernel<<<264, 256, 0, stream>>>(W_ih, mlp_w, pred_w, Wihb, Baug);
  embed_kernel<<<32768, 256, 0, stream>>>(qseq, cseq, q2c, q2cm, cemb, remb,
                                          pred_w, interb, C3);
  gemm_mfma_kernel<<<dim3(1024, 6), 256, 0, stream>>>(interb, Wihb, b_ih, Xp, 384);
  gru_kernel<<<16, 512, 0, stream>>>(Xp, W_hh, b_hh, rnn);
  gemm_score_kernel<<<1024, 256, 0, stream>>>(rnn, Baug, mlp_b, sim_w,
                                              sbuf, D1, D2);
  attn_final_kernel<<<64, 128, 0, stream>>>(sbuf, D1, D2, C3, pred_b, out);
}